// Round 8
// baseline (211.767 us; speedup 1.0000x reference)
//
#include <hip/hip_runtime.h>
#include <math.h>

#define NUSER 2560
#define NITEM 3584
#define NN    6144
#define EDIM  64
#define NNZ   200000
#define DQK   256
#define KTOP  5
#define SPLITS 16
#define TPS    3          // 48 cand tiles / 16 splits
#define CK     4          // coarse candidates kept per (row, split); 16*4=64 rescored
#define ELLW   96         // padded-ELL row capacity (max row nnz ~58 at 200k/6144)
#define TPB   256
#define QKV_BLOCKS 576    // 96 rowtiles x 2 dtiles x 3 matrices
#define TOPK_BLOCKS (96 * SPLITS)   // 1536
#define BSTR  72          // Bh LDS row stride in shorts (144B -> conflict-light ds_read_b128)

typedef __attribute__((ext_vector_type(8))) short bf16x8;
typedef __attribute__((ext_vector_type(4))) float f32x4;

__device__ __forceinline__ unsigned short f2bf(float f) {
    unsigned int b = __float_as_uint(f);
    unsigned int r = (b + 0x7FFFu + ((b >> 16) & 1u)) >> 16;
    return (unsigned short)r;
}
__device__ __forceinline__ int pack2(float a, float b) {
    return (int)f2bf(a) | ((int)f2bf(b) << 16);
}
__device__ __forceinline__ void ell_unpack(long long v, int* col, float* w) {
    *col = (int)(v & 0xffffffffLL);
    *w   = __int_as_float((int)(v >> 32));
}
__device__ __forceinline__ unsigned umax(unsigned a, unsigned b) { return a > b ? a : b; }
__device__ __forceinline__ unsigned umin(unsigned a, unsigned b) { return a < b ? a : b; }

// ================================================================ padded-ELL build (one pass, both matrices)
__global__ void build_kernel(const int* __restrict__ nr, const int* __restrict__ nc,
                             const float* __restrict__ nv,
                             const int* __restrict__ ar, const int* __restrict__ ac,
                             int* __restrict__ cnt_n, int* __restrict__ cnt_a,
                             long long* __restrict__ cv_n, int* __restrict__ cv_a) {
    int g = blockIdx.x * TPB + threadIdx.x;
    if (g < NNZ) {
        int r = __builtin_nontemporal_load(&nr[g]);
        int c = __builtin_nontemporal_load(&nc[g]);
        float v = __builtin_nontemporal_load(&nv[g]);
        int slot = atomicAdd(&cnt_n[r], 1);
        long long pk = (unsigned int)c | ((long long)(unsigned int)__float_as_int(v) << 32);
        __builtin_nontemporal_store(pk, &cv_n[r * ELLW + slot]);
    } else if (g < 2 * NNZ) {
        int h = g - NNZ;
        int r = __builtin_nontemporal_load(&ar[h]);
        int c = __builtin_nontemporal_load(&ac[h]);
        int slot = atomicAdd(&cnt_a[r], 1);
        __builtin_nontemporal_store(c, &cv_a[r * ELLW + slot]);
    }
}

// ================================================================ ELL SpMM, wave-per-row, x8 unroll
__global__ __launch_bounds__(TPB) void spmm_ell_emb_kernel(
        const int* __restrict__ cnt, const long long* __restrict__ cv,
        const float* __restrict__ user, const float* __restrict__ item,
        float* __restrict__ dst) {
    int r = blockIdx.x * 4 + (threadIdx.x >> 6);
    int lane = threadIdx.x & 63;
    int s = r * ELLW, e = s + cnt[r];
    float a[8];
#pragma unroll
    for (int u = 0; u < 8; ++u) a[u] = 0.f;
    int j = s, n8 = s + ((e - s) & ~7);
    for (; j < n8; j += 8) {
        int col[8]; float w[8];
#pragma unroll
        for (int u = 0; u < 8; ++u) ell_unpack(__builtin_nontemporal_load(&cv[j + u]), &col[u], &w[u]);
#pragma unroll
        for (int u = 0; u < 8; ++u) {
            float x = (col[u] < NUSER) ? user[col[u] * EDIM + lane]
                                       : item[(col[u] - NUSER) * EDIM + lane];
            a[u] = fmaf(w[u], x, a[u]);
        }
    }
    for (; j < e; ++j) {
        int col; float w;
        ell_unpack(__builtin_nontemporal_load(&cv[j]), &col, &w);
        float x = (col < NUSER) ? user[col * EDIM + lane] : item[(col - NUSER) * EDIM + lane];
        a[0] = fmaf(w, x, a[0]);
    }
    dst[r * EDIM + lane] = ((a[0] + a[1]) + (a[2] + a[3])) + ((a[4] + a[5]) + (a[6] + a[7]));
}

// second hop also emits a bf16 copy of ego2 (consumed by the topk tile staging)
__global__ __launch_bounds__(TPB) void spmm_ell_kernel(
        const int* __restrict__ cnt, const long long* __restrict__ cv,
        const float* __restrict__ src, float* __restrict__ dst,
        unsigned short* __restrict__ dsth) {
    int r = blockIdx.x * 4 + (threadIdx.x >> 6);
    int lane = threadIdx.x & 63;
    int s = r * ELLW, e = s + cnt[r];
    float a[8];
#pragma unroll
    for (int u = 0; u < 8; ++u) a[u] = 0.f;
    int j = s, n8 = s + ((e - s) & ~7);
    for (; j < n8; j += 8) {
        int col[8]; float w[8];
#pragma unroll
        for (int u = 0; u < 8; ++u) ell_unpack(__builtin_nontemporal_load(&cv[j + u]), &col[u], &w[u]);
#pragma unroll
        for (int u = 0; u < 8; ++u)
            a[u] = fmaf(w[u], src[col[u] * EDIM + lane], a[u]);
    }
    for (; j < e; ++j) {
        int col; float w;
        ell_unpack(__builtin_nontemporal_load(&cv[j]), &col, &w);
        a[0] = fmaf(w, src[col * EDIM + lane], a[0]);
    }
    float res = ((a[0] + a[1]) + (a[2] + a[3])) + ((a[4] + a[5]) + (a[6] + a[7]));
    dst[r * EDIM + lane]  = res;
    dsth[r * EDIM + lane] = f2bf(res);
}

// Qm = ego2 + 0.5*(A@ego2) ; outmean = 0.5*(ego0+ego1)  (A weights implicit 1.0)
__global__ __launch_bounds__(TPB) void qm_mean_kernel(
        const int* __restrict__ cnt, const int* __restrict__ cv,
        const float* __restrict__ ego2, const float* __restrict__ ego1,
        const float* __restrict__ user, const float* __restrict__ item,
        float* __restrict__ Qm, float* __restrict__ outmean) {
    int r = blockIdx.x * 4 + (threadIdx.x >> 6);
    int lane = threadIdx.x & 63;
    int s = r * ELLW, e = s + cnt[r];
    float a[8];
#pragma unroll
    for (int u = 0; u < 8; ++u) a[u] = 0.f;
    int j = s, n8 = s + ((e - s) & ~7);
    for (; j < n8; j += 8) {
        int col[8];
#pragma unroll
        for (int u = 0; u < 8; ++u) col[u] = __builtin_nontemporal_load(&cv[j + u]);
#pragma unroll
        for (int u = 0; u < 8; ++u)
            a[u] += ego2[col[u] * EDIM + lane];
    }
    for (; j < e; ++j) {
        int col = __builtin_nontemporal_load(&cv[j]);
        a[0] += ego2[col * EDIM + lane];
    }
    float acc = ((a[0] + a[1]) + (a[2] + a[3])) + ((a[4] + a[5]) + (a[6] + a[7]));
    int o = r * EDIM + lane;
    Qm[o] = ego2[o] + 0.5f * acc;
    float e0v = (r < NUSER) ? user[o] : item[o - NUSER * EDIM];
    outmean[o] = 0.5f * (e0v + ego1[o]);
}

// ================================================================ fused QKV-GEMM + MFMA coarse top-4x16
// CHAMPION structure (196.4 us): LDS 26624 B, launch_bounds(TPB,6) — the VGPR-40
// config measured fastest in wall time; do NOT "fix" the spills (R1/R2 lesson).
// This round: SPLITS 8->16 (TPS 3, CK 4) halves the serial merge per row.
__global__ __launch_bounds__(TPB, 6) void qkv_topk_kernel(
        const float* __restrict__ ego2, const unsigned short* __restrict__ eg2h,
        const float* __restrict__ Wq, const float* __restrict__ bq,
        const float* __restrict__ Wk, const float* __restrict__ bk,
        const float* __restrict__ Wv, const float* __restrict__ bv,
        float* __restrict__ Qa, float* __restrict__ Ka, float* __restrict__ Va,
        const float* __restrict__ Qm,
        int* __restrict__ pidx) {
    __shared__ __align__(16) short smem[13312];   // 26624 B
    int t = threadIdx.x;

    if (blockIdx.x < QKV_BLOCKS) {
        // ---------------- QKV GEMM path (fp32, E split in two K-halves of 32) ----------------
        int tx = t & 15, ty = t >> 4;
        int id = blockIdx.x;
        int bz = id / 192, rem = id % 192, by = rem / 96, bx = rem % 96;
        const float* W; const float* b; float* out;
        if (bz == 0)      { W = Wq; b = bq; out = Qa; }
        else if (bz == 1) { W = Wk; b = bk; out = Ka; }
        else              { W = Wv; b = bv; out = Va; }
        float* As = (float*)smem;      // [32][64]   8 KB
        float* Bs = As + 2048;         // [32][128] 16 KB
        int r0 = bx * 64, d0 = by * 128;
        float acc[4][8];
#pragma unroll
        for (int i = 0; i < 4; ++i)
#pragma unroll
            for (int j = 0; j < 8; ++j) acc[i][j] = 0.f;

        for (int h = 0; h < 2; ++h) {
            if (h) __syncthreads();    // previous K-half fully consumed
            {
                int r = t & 63, eb = (t >> 6) * 8;
#pragma unroll
                for (int rep = 0; rep < 2; ++rep) {
                    int e0 = eb + rep * 4;
                    float4 v = *(const float4*)&ego2[(r0 + r) * EDIM + h * 32 + e0];
                    As[(e0 + 0) * 64 + r] = v.x; As[(e0 + 1) * 64 + r] = v.y;
                    As[(e0 + 2) * 64 + r] = v.z; As[(e0 + 3) * 64 + r] = v.w;
                }
            }
            {
                int d = t & 127, eb = (t >> 7) * 16;
#pragma unroll
                for (int rep = 0; rep < 4; ++rep) {
                    int e0 = eb + rep * 4;
                    float4 v = *(const float4*)&W[(d0 + d) * EDIM + h * 32 + e0];
                    Bs[(e0 + 0) * 128 + d] = v.x; Bs[(e0 + 1) * 128 + d] = v.y;
                    Bs[(e0 + 2) * 128 + d] = v.z; Bs[(e0 + 3) * 128 + d] = v.w;
                }
            }
            __syncthreads();
#pragma unroll 4
            for (int e = 0; e < 32; ++e) {
                float4 a  = *(const float4*)&As[e * 64 + ty * 4];
                float4 b0 = *(const float4*)&Bs[e * 128 + tx * 4];
                float4 b1 = *(const float4*)&Bs[e * 128 + 64 + tx * 4];
                float ar[4] = {a.x, a.y, a.z, a.w};
#pragma unroll
                for (int i = 0; i < 4; ++i) {
                    acc[i][0] = fmaf(ar[i], b0.x, acc[i][0]);
                    acc[i][1] = fmaf(ar[i], b0.y, acc[i][1]);
                    acc[i][2] = fmaf(ar[i], b0.z, acc[i][2]);
                    acc[i][3] = fmaf(ar[i], b0.w, acc[i][3]);
                    acc[i][4] = fmaf(ar[i], b1.x, acc[i][4]);
                    acc[i][5] = fmaf(ar[i], b1.y, acc[i][5]);
                    acc[i][6] = fmaf(ar[i], b1.z, acc[i][6]);
                    acc[i][7] = fmaf(ar[i], b1.w, acc[i][7]);
                }
            }
        }
        float4 bias0 = *(const float4*)&b[d0 + tx * 4];
        float4 bias1 = *(const float4*)&b[d0 + 64 + tx * 4];
#pragma unroll
        for (int i = 0; i < 4; ++i) {
            int r = r0 + ty * 4 + i;
            float4 o0 = make_float4(acc[i][0] + bias0.x, acc[i][1] + bias0.y,
                                    acc[i][2] + bias0.z, acc[i][3] + bias0.w);
            float4 o1 = make_float4(acc[i][4] + bias1.x, acc[i][5] + bias1.y,
                                    acc[i][6] + bias1.z, acc[i][7] + bias1.w);
            *(float4*)&out[r * DQK + d0 + tx * 4] = o0;
            *(float4*)&out[r * DQK + d0 + 64 + tx * 4] = o1;
        }
        return;
    }

    // ---------------- MFMA coarse top-4 x 16 splits ----------------
    // block: 64 rows x (TPS=3 x 128 cands). wave w: rows r0+w*16..+15.
    // C layout: col=lane&15, row=(lane>>4)*4+reg  [m89/m120-verified]
    // Keys: bits of (sim+16.0), low 6 bits = local id (tile*8+ch).
    int id = blockIdx.x - QKV_BLOCKS;
    int rb = id % 96, sp = id / 96;
    int r0 = rb * 64;
    int w = t >> 6, lane = t & 63, lq = lane >> 4, lc = lane & 15;

    short* Ah = (short*)smem;            // [64][64] bf16 row-major, 8 KB
    short* Bh = Ah + 64 * EDIM;          // [128][BSTR=72] bf16 padded, 18 KB

    { // stage A from fp32 Qm (once per block): thread covers 16 floats
        int row = t >> 2, seg = t & 3;
        const float4* src = (const float4*)&Qm[(size_t)(r0 + row) * EDIM + seg * 16];
        float4 f0 = src[0], f1 = src[1], f2 = src[2], f3 = src[3];
        int4 p0, p1;
        p0.x = pack2(f0.x, f0.y); p0.y = pack2(f0.z, f0.w);
        p0.z = pack2(f1.x, f1.y); p0.w = pack2(f1.z, f1.w);
        p1.x = pack2(f2.x, f2.y); p1.y = pack2(f2.z, f2.w);
        p1.z = pack2(f3.x, f3.y); p1.w = pack2(f3.z, f3.w);
        *(int4*)&Ah[row * EDIM + seg * 16] = p0;
        *(int4*)&Ah[row * EDIM + seg * 16 + 8] = p1;
    }

    // per-thread B staging coords: v = t + 256*rep; row = v>>3, slot = v&7 (int4 of bf16)
    int4 pr[4];
    { // prefetch tile 0 (already bf16 -> pure copy, no conversion)
        int c0 = (sp * TPS) * 128;
#pragma unroll
        for (int rep = 0; rep < 4; ++rep) {
            int v = t + 256 * rep;
            pr[rep] = *(const int4*)&eg2h[(size_t)(c0 + (v >> 3)) * EDIM + (v & 7) * 8];
        }
    }

    unsigned t3[4][3];
#pragma unroll
    for (int i = 0; i < 4; ++i)
#pragma unroll
        for (int k = 0; k < 3; ++k) t3[i][k] = 0u;

    const unsigned KMASK = 0xFFFFFFC0u;
    bf16x8 af0, af1;
    for (int tile = 0; tile < TPS; ++tile) {
        __syncthreads();    // previous tile's B consumed (tile0: A-store also drains)
#pragma unroll
        for (int rep = 0; rep < 4; ++rep) {
            int v = t + 256 * rep;
            *(int4*)&Bh[(v >> 3) * BSTR + (v & 7) * 8] = pr[rep];
        }
        if (tile + 1 < TPS) { // prefetch next tile; lands during this tile's compute
            int c1 = (sp * TPS + tile + 1) * 128;
#pragma unroll
            for (int rep = 0; rep < 4; ++rep) {
                int v = t + 256 * rep;
                pr[rep] = *(const int4*)&eg2h[(size_t)(c1 + (v >> 3)) * EDIM + (v & 7) * 8];
            }
        }
        __syncthreads();
        if (tile == 0) {
            af0 = *(const bf16x8*)&Ah[(w * 16 + lc) * EDIM + lq * 8];
            af1 = *(const bf16x8*)&Ah[(w * 16 + lc) * EDIM + 32 + lq * 8];
        }

        int tb = tile * 8;
#pragma unroll
        for (int ch = 0; ch < 8; ++ch) {
            bf16x8 b0 = *(const bf16x8*)&Bh[(ch * 16 + lc) * BSTR + lq * 8];
            bf16x8 b1 = *(const bf16x8*)&Bh[(ch * 16 + lc) * BSTR + 32 + lq * 8];
            f32x4 acc = {16.f, 16.f, 16.f, 16.f};   // bias so keys sort as unsigned
            acc = __builtin_amdgcn_mfma_f32_16x16x32_bf16(af0, b0, acc, 0, 0, 0);
            acc = __builtin_amdgcn_mfma_f32_16x16x32_bf16(af1, b1, acc, 0, 0, 0);
            unsigned lid = (unsigned)(tb + ch);
#pragma unroll
            for (int reg = 0; reg < 4; ++reg) {
                unsigned key = (__float_as_uint(acc[reg]) & KMASK) | lid;
                unsigned v0 = t3[reg][0], v1 = t3[reg][1], v2 = t3[reg][2];
                t3[reg][0] = umax(v0, key);
                t3[reg][1] = umax(v1, umin(v0, key));
                t3[reg][2] = umax(v2, umin(v1, key));
            }
        }
    }

    // merge 16 lanes' top-3 -> split top-4: 4 rounds of u32 max-reduce.
    // compare value = (key & ~63) | (lc<<2): unique per lane -> exactly one winner;
    // winner decodes global cand index from its own key (lid = tile*8+ch, own lc).
    int sb128 = sp * (TPS * 128);
    unsigned lc2 = (unsigned)(lc << 2);
#pragma unroll
    for (int i = 0; i < 4; ++i) {
        int row = r0 + w * 16 + lq * 4 + i;
        int base = (row * SPLITS + sp) * CK;
        unsigned a0 = t3[i][0], a1 = t3[i][1], a2 = t3[i][2];
#pragma unroll
        for (int k = 0; k < CK; ++k) {
            unsigned vk = (a0 & KMASK) | lc2;
            unsigned bvv = vk;
#pragma unroll
            for (int off = 1; off < 16; off <<= 1)
                bvv = umax(bvv, (unsigned)__shfl_xor((int)bvv, off, 64));
            if (vk == bvv) {
                unsigned lid = a0 & 63u;
                pidx[base + k] = sb128 + (int)((lid >> 3) << 7) + (int)((lid & 7) << 4) + lc;
                a0 = a1; a1 = a2; a2 = 0u;
            }
        }
    }
}

// ================================================================ exact rescore (coalesced) + u32-key top-5 + attention
__global__ __launch_bounds__(TPB) void attn_kernel(
        const float* __restrict__ Qm, const float* __restrict__ ego2,
        const float* __restrict__ Qa, const float* __restrict__ Ka, const float* __restrict__ Va,
        const int* __restrict__ pidx, float* __restrict__ out) {
    __shared__ float sb[4][64];
    int wv = threadIdx.x >> 6, lane = threadIdx.x & 63;
    int r = blockIdx.x * 4 + wv;
    int ci0 = pidx[r * (SPLITS * CK) + lane];     // lane's cand (64 unique: splits partition cands)
    int part = lane & 3;

    const float4* qmp = (const float4*)(Qm + (size_t)r * EDIM + part * 16);
    float4 q0 = qmp[0], q1 = qmp[1], q2 = qmp[2], q3 = qmp[3];

#pragma unroll
    for (int p = 0; p < 4; ++p) {
        int j = p * 16 + (lane >> 2);
        int c = __shfl(ci0, j, 64);
        const float4* ep = (const float4*)(ego2 + (size_t)c * EDIM + part * 16);
        float4 e0 = ep[0], e1 = ep[1], e2 = ep[2], e3 = ep[3];
        float s = 0.f;
        s = fmaf(q0.x, e0.x, s); s = fmaf(q0.y, e0.y, s); s = fmaf(q0.z, e0.z, s); s = fmaf(q0.w, e0.w, s);
        s = fmaf(q1.x, e1.x, s); s = fmaf(q1.y, e1.y, s); s = fmaf(q1.z, e1.z, s); s = fmaf(q1.w, e1.w, s);
        s = fmaf(q2.x, e2.x, s); s = fmaf(q2.y, e2.y, s); s = fmaf(q2.z, e2.z, s); s = fmaf(q2.w, e2.w, s);
        s = fmaf(q3.x, e3.x, s); s = fmaf(q3.y, e3.y, s); s = fmaf(q3.z, e3.z, s); s = fmaf(q3.w, e3.w, s);
        s += __shfl_xor(s, 1, 64);
        s += __shfl_xor(s, 2, 64);
        if (part == 0) sb[wv][j] = s;
    }
    float sv = sb[wv][lane];

    // top-5 via packed u32 keys: (bits(sv+16) & ~63) | lane. Unique per lane,
    // monotone in sv (|sv|<16, validated by the same bias in the coarse keys).
    // One u32 max-reduce + one dynamic shfl per round, vs (val,idx) pair compares.
    unsigned mykey = (__float_as_uint(sv + 16.f) & 0xFFFFFFC0u) | (unsigned)lane;
    int cI[KTOP];
    unsigned lim = 0xFFFFFFFFu;
#pragma unroll
    for (int k = 0; k < KTOP; ++k) {
        unsigned vk = (mykey < lim) ? mykey : 0u;
        unsigned bk = vk;
#pragma unroll
        for (int off = 1; off < 64; off <<= 1)
            bk = umax(bk, (unsigned)__shfl_xor((int)bk, off, 64));
        cI[k] = __shfl(ci0, (int)(bk & 63u), 64);   // winner's cand idx -> all lanes
        lim = bk;
    }

    float4 q = *(const float4*)&Qa[r * DQK + lane * 4];
    float sc[KTOP];
#pragma unroll
    for (int k = 0; k < KTOP; ++k) {
        float4 kk = *(const float4*)&Ka[cI[k] * DQK + lane * 4];
        float p = q.x * kk.x + q.y * kk.y + q.z * kk.z + q.w * kk.w;
#pragma unroll
        for (int off = 32; off; off >>= 1) p += __shfl_xor(p, off, 64);
        sc[k] = p * 0.0625f;   // 1/sqrt(256)
    }
    float m = sc[0];
#pragma unroll
    for (int k = 1; k < KTOP; ++k) m = fmaxf(m, sc[k]);
    float wgt[KTOP], ssum = 0.f;
#pragma unroll
    for (int k = 0; k < KTOP; ++k) { wgt[k] = expf(sc[k] - m); ssum += wgt[k]; }
    float inv = 1.f / ssum;
    float4 o = make_float4(0.f, 0.f, 0.f, 0.f);
#pragma unroll
    for (int k = 0; k < KTOP; ++k) {
        float4 vv = *(const float4*)&Va[cI[k] * DQK + lane * 4];
        float a = wgt[k] * inv;
        o.x = fmaf(a, vv.x, o.x); o.y = fmaf(a, vv.y, o.y);
        o.z = fmaf(a, vv.z, o.z); o.w = fmaf(a, vv.w, o.w);
    }
    *(float4*)&out[r * DQK + lane * 4] = o;
}

// ================================================================ launch
extern "C" void kernel_launch(void* const* d_in, const int* in_sizes, int n_in,
                              void* d_out, int out_size, void* d_ws, size_t ws_size,
                              hipStream_t stream) {
    const float* user  = (const float*)d_in[0];
    const float* item  = (const float*)d_in[1];
    const int*   nrows = (const int*)d_in[2];
    const int*   ncols = (const int*)d_in[3];
    const float* nvals = (const float*)d_in[4];
    const int*   arows = (const int*)d_in[5];
    const int*   acols = (const int*)d_in[6];
    const float* Wq = (const float*)d_in[8];  const float* bq = (const float*)d_in[9];
    const float* Wk = (const float*)d_in[10]; const float* bk = (const float*)d_in[11];
    const float* Wv = (const float*)d_in[12]; const float* bv = (const float*)d_in[13];
    float* out = (float*)d_out;
    float* ws  = (float*)d_ws;

    const int NE  = NN * EDIM;             // 393216
    const int NQK = NN * DQK;              // 1572864
    float* ego1 = ws;
    float* ego2 = ws + NE;
    float* Qm   = ws + 2 * NE;
    float* Qa   = ws + 3 * NE;
    float* Ka   = Qa + NQK;
    float* Va   = Ka + NQK;
    int*   pidx = (int*)(Va + NQK);                       // NN*SPLITS*CK ints
    unsigned short* eg2h = (unsigned short*)(pidx + NN * SPLITS * CK);  // NN*EDIM bf16

    // ELL scratch aliased over Qa..Va (dead until qkv_topk)
    int* ell    = (int*)Qa;
    int* cnt_n  = ell;                     // 6144
    int* cnt_a  = ell + 6144;              // 6144
    long long* cv_n = (long long*)(ell + 12288);   // 6144*96 x 8B
    int* cv_a   = (int*)(cv_n + NN * ELLW);        // 6144*96 x 4B

    hipMemsetAsync(cnt_n, 0, 12288 * sizeof(int), stream);
    build_kernel<<<(2 * NNZ + TPB - 1) / TPB, TPB, 0, stream>>>(nrows, ncols, nvals,
                                                                arows, acols,
                                                                cnt_n, cnt_a, cv_n, cv_a);
    spmm_ell_emb_kernel<<<NN / 4, TPB, 0, stream>>>(cnt_n, cv_n, user, item, ego1);
    spmm_ell_kernel<<<NN / 4, TPB, 0, stream>>>(cnt_n, cv_n, ego1, ego2, eg2h);
    qm_mean_kernel<<<NN / 4, TPB, 0, stream>>>(cnt_a, cv_a, ego2, ego1, user, item, Qm, out);
    qkv_topk_kernel<<<QKV_BLOCKS + TOPK_BLOCKS, TPB, 0, stream>>>(
        ego2, eg2h, Wq, bq, Wk, bk, Wv, bv, Qa, Ka, Va, Qm, pidx);
    attn_kernel<<<NN / 4, TPB, 0, stream>>>(Qm, ego2, Qa, Ka, Va, pidx, out + NE);
}

// Round 9
// 196.360 us; speedup vs baseline: 1.0785x; 1.0785x over previous
//
#include <hip/hip_runtime.h>
#include <math.h>

#define NUSER 2560
#define NITEM 3584
#define NN    6144
#define EDIM  64
#define NNZ   200000
#define DQK   256
#define KTOP  5
#define SPLITS 8
#define TPS    6          // 48 cand tiles / 8 splits
#define CK     8          // coarse candidates kept per (row, split); 8*8=64 rescored
#define ELLW   96         // padded-ELL row capacity (max row nnz ~58 at 200k/6144)
#define TPB   256
#define QKV_BLOCKS 576    // 96 rowtiles x 2 dtiles x 3 matrices
#define TOPK_BLOCKS (96 * SPLITS)
#define BSTR  72          // Bh LDS row stride in shorts (144B -> conflict-light ds_read_b128)

typedef __attribute__((ext_vector_type(8))) short bf16x8;
typedef __attribute__((ext_vector_type(4))) float f32x4;

__device__ __forceinline__ unsigned short f2bf(float f) {
    unsigned int b = __float_as_uint(f);
    unsigned int r = (b + 0x7FFFu + ((b >> 16) & 1u)) >> 16;
    return (unsigned short)r;
}
__device__ __forceinline__ int pack2(float a, float b) {
    return (int)f2bf(a) | ((int)f2bf(b) << 16);
}
__device__ __forceinline__ void ell_unpack(long long v, int* col, float* w) {
    *col = (int)(v & 0xffffffffLL);
    *w   = __int_as_float((int)(v >> 32));
}
__device__ __forceinline__ unsigned umax(unsigned a, unsigned b) { return a > b ? a : b; }
__device__ __forceinline__ unsigned umin(unsigned a, unsigned b) { return a < b ? a : b; }

// ================================================================ padded-ELL build (one pass, both matrices)
__global__ void build_kernel(const int* __restrict__ nr, const int* __restrict__ nc,
                             const float* __restrict__ nv,
                             const int* __restrict__ ar, const int* __restrict__ ac,
                             int* __restrict__ cnt_n, int* __restrict__ cnt_a,
                             long long* __restrict__ cv_n, int* __restrict__ cv_a) {
    int g = blockIdx.x * TPB + threadIdx.x;
    if (g < NNZ) {
        int r = __builtin_nontemporal_load(&nr[g]);
        int c = __builtin_nontemporal_load(&nc[g]);
        float v = __builtin_nontemporal_load(&nv[g]);
        int slot = atomicAdd(&cnt_n[r], 1);
        long long pk = (unsigned int)c | ((long long)(unsigned int)__float_as_int(v) << 32);
        __builtin_nontemporal_store(pk, &cv_n[r * ELLW + slot]);
    } else if (g < 2 * NNZ) {
        int h = g - NNZ;
        int r = __builtin_nontemporal_load(&ar[h]);
        int c = __builtin_nontemporal_load(&ac[h]);
        int slot = atomicAdd(&cnt_a[r], 1);
        __builtin_nontemporal_store(c, &cv_a[r * ELLW + slot]);
    }
}

// ================================================================ ELL SpMM, wave-per-row, x8 unroll
__global__ __launch_bounds__(TPB) void spmm_ell_emb_kernel(
        const int* __restrict__ cnt, const long long* __restrict__ cv,
        const float* __restrict__ user, const float* __restrict__ item,
        float* __restrict__ dst) {
    int r = blockIdx.x * 4 + (threadIdx.x >> 6);
    int lane = threadIdx.x & 63;
    int s = r * ELLW, e = s + cnt[r];
    float a[8];
#pragma unroll
    for (int u = 0; u < 8; ++u) a[u] = 0.f;
    int j = s, n8 = s + ((e - s) & ~7);
    for (; j < n8; j += 8) {
        int col[8]; float w[8];
#pragma unroll
        for (int u = 0; u < 8; ++u) ell_unpack(__builtin_nontemporal_load(&cv[j + u]), &col[u], &w[u]);
#pragma unroll
        for (int u = 0; u < 8; ++u) {
            float x = (col[u] < NUSER) ? user[col[u] * EDIM + lane]
                                       : item[(col[u] - NUSER) * EDIM + lane];
            a[u] = fmaf(w[u], x, a[u]);
        }
    }
    for (; j < e; ++j) {
        int col; float w;
        ell_unpack(__builtin_nontemporal_load(&cv[j]), &col, &w);
        float x = (col < NUSER) ? user[col * EDIM + lane] : item[(col - NUSER) * EDIM + lane];
        a[0] = fmaf(w, x, a[0]);
    }
    dst[r * EDIM + lane] = ((a[0] + a[1]) + (a[2] + a[3])) + ((a[4] + a[5]) + (a[6] + a[7]));
}

// second hop also emits a bf16 copy of ego2 (consumed by the topk tile staging)
__global__ __launch_bounds__(TPB) void spmm_ell_kernel(
        const int* __restrict__ cnt, const long long* __restrict__ cv,
        const float* __restrict__ src, float* __restrict__ dst,
        unsigned short* __restrict__ dsth) {
    int r = blockIdx.x * 4 + (threadIdx.x >> 6);
    int lane = threadIdx.x & 63;
    int s = r * ELLW, e = s + cnt[r];
    float a[8];
#pragma unroll
    for (int u = 0; u < 8; ++u) a[u] = 0.f;
    int j = s, n8 = s + ((e - s) & ~7);
    for (; j < n8; j += 8) {
        int col[8]; float w[8];
#pragma unroll
        for (int u = 0; u < 8; ++u) ell_unpack(__builtin_nontemporal_load(&cv[j + u]), &col[u], &w[u]);
#pragma unroll
        for (int u = 0; u < 8; ++u)
            a[u] = fmaf(w[u], src[col[u] * EDIM + lane], a[u]);
    }
    for (; j < e; ++j) {
        int col; float w;
        ell_unpack(__builtin_nontemporal_load(&cv[j]), &col, &w);
        a[0] = fmaf(w, src[col * EDIM + lane], a[0]);
    }
    float res = ((a[0] + a[1]) + (a[2] + a[3])) + ((a[4] + a[5]) + (a[6] + a[7]));
    dst[r * EDIM + lane]  = res;
    dsth[r * EDIM + lane] = f2bf(res);
}

// Qm = ego2 + 0.5*(A@ego2) ; outmean = 0.5*(ego0+ego1)  (A weights implicit 1.0)
__global__ __launch_bounds__(TPB) void qm_mean_kernel(
        const int* __restrict__ cnt, const int* __restrict__ cv,
        const float* __restrict__ ego2, const float* __restrict__ ego1,
        const float* __restrict__ user, const float* __restrict__ item,
        float* __restrict__ Qm, float* __restrict__ outmean) {
    int r = blockIdx.x * 4 + (threadIdx.x >> 6);
    int lane = threadIdx.x & 63;
    int s = r * ELLW, e = s + cnt[r];
    float a[8];
#pragma unroll
    for (int u = 0; u < 8; ++u) a[u] = 0.f;
    int j = s, n8 = s + ((e - s) & ~7);
    for (; j < n8; j += 8) {
        int col[8];
#pragma unroll
        for (int u = 0; u < 8; ++u) col[u] = __builtin_nontemporal_load(&cv[j + u]);
#pragma unroll
        for (int u = 0; u < 8; ++u)
            a[u] += ego2[col[u] * EDIM + lane];
    }
    for (; j < e; ++j) {
        int col = __builtin_nontemporal_load(&cv[j]);
        a[0] += ego2[col * EDIM + lane];
    }
    float acc = ((a[0] + a[1]) + (a[2] + a[3])) + ((a[4] + a[5]) + (a[6] + a[7]));
    int o = r * EDIM + lane;
    Qm[o] = ego2[o] + 0.5f * acc;
    float e0v = (r < NUSER) ? user[o] : item[o - NUSER * EDIM];
    outmean[o] = 0.5f * (e0v + ego1[o]);
}

// ================================================================ fused QKV-GEMM + MFMA coarse top-8
// CHAMPION (196.4 us measured): LDS 26624 B, launch_bounds(TPB,6), SPLITS 8.
// The VGPR-40 allocation spills (~54 MB WRITE), but every "fix" measured slower:
// min-waves 3 (200.8), kernel split (202.5), 48KB merge (215.9), direct-global B
// (206.8), SPLITS16 (211.8 — spill scales with block count). Do not deviate.
__global__ __launch_bounds__(TPB, 6) void qkv_topk_kernel(
        const float* __restrict__ ego2, const unsigned short* __restrict__ eg2h,
        const float* __restrict__ Wq, const float* __restrict__ bq,
        const float* __restrict__ Wk, const float* __restrict__ bk,
        const float* __restrict__ Wv, const float* __restrict__ bv,
        float* __restrict__ Qa, float* __restrict__ Ka, float* __restrict__ Va,
        const float* __restrict__ Qm,
        int* __restrict__ pidx) {
    __shared__ __align__(16) short smem[13312];   // 26624 B
    int t = threadIdx.x;

    if (blockIdx.x < QKV_BLOCKS) {
        // ---------------- QKV GEMM path (fp32, E split in two K-halves of 32) ----------------
        int tx = t & 15, ty = t >> 4;
        int id = blockIdx.x;
        int bz = id / 192, rem = id % 192, by = rem / 96, bx = rem % 96;
        const float* W; const float* b; float* out;
        if (bz == 0)      { W = Wq; b = bq; out = Qa; }
        else if (bz == 1) { W = Wk; b = bk; out = Ka; }
        else              { W = Wv; b = bv; out = Va; }
        float* As = (float*)smem;      // [32][64]   8 KB
        float* Bs = As + 2048;         // [32][128] 16 KB
        int r0 = bx * 64, d0 = by * 128;
        float acc[4][8];
#pragma unroll
        for (int i = 0; i < 4; ++i)
#pragma unroll
            for (int j = 0; j < 8; ++j) acc[i][j] = 0.f;

        for (int h = 0; h < 2; ++h) {
            if (h) __syncthreads();    // previous K-half fully consumed
            {
                int r = t & 63, eb = (t >> 6) * 8;
#pragma unroll
                for (int rep = 0; rep < 2; ++rep) {
                    int e0 = eb + rep * 4;
                    float4 v = *(const float4*)&ego2[(r0 + r) * EDIM + h * 32 + e0];
                    As[(e0 + 0) * 64 + r] = v.x; As[(e0 + 1) * 64 + r] = v.y;
                    As[(e0 + 2) * 64 + r] = v.z; As[(e0 + 3) * 64 + r] = v.w;
                }
            }
            {
                int d = t & 127, eb = (t >> 7) * 16;
#pragma unroll
                for (int rep = 0; rep < 4; ++rep) {
                    int e0 = eb + rep * 4;
                    float4 v = *(const float4*)&W[(d0 + d) * EDIM + h * 32 + e0];
                    Bs[(e0 + 0) * 128 + d] = v.x; Bs[(e0 + 1) * 128 + d] = v.y;
                    Bs[(e0 + 2) * 128 + d] = v.z; Bs[(e0 + 3) * 128 + d] = v.w;
                }
            }
            __syncthreads();
#pragma unroll 4
            for (int e = 0; e < 32; ++e) {
                float4 a  = *(const float4*)&As[e * 64 + ty * 4];
                float4 b0 = *(const float4*)&Bs[e * 128 + tx * 4];
                float4 b1 = *(const float4*)&Bs[e * 128 + 64 + tx * 4];
                float ar[4] = {a.x, a.y, a.z, a.w};
#pragma unroll
                for (int i = 0; i < 4; ++i) {
                    acc[i][0] = fmaf(ar[i], b0.x, acc[i][0]);
                    acc[i][1] = fmaf(ar[i], b0.y, acc[i][1]);
                    acc[i][2] = fmaf(ar[i], b0.z, acc[i][2]);
                    acc[i][3] = fmaf(ar[i], b0.w, acc[i][3]);
                    acc[i][4] = fmaf(ar[i], b1.x, acc[i][4]);
                    acc[i][5] = fmaf(ar[i], b1.y, acc[i][5]);
                    acc[i][6] = fmaf(ar[i], b1.z, acc[i][6]);
                    acc[i][7] = fmaf(ar[i], b1.w, acc[i][7]);
                }
            }
        }
        float4 bias0 = *(const float4*)&b[d0 + tx * 4];
        float4 bias1 = *(const float4*)&b[d0 + 64 + tx * 4];
#pragma unroll
        for (int i = 0; i < 4; ++i) {
            int r = r0 + ty * 4 + i;
            float4 o0 = make_float4(acc[i][0] + bias0.x, acc[i][1] + bias0.y,
                                    acc[i][2] + bias0.z, acc[i][3] + bias0.w);
            float4 o1 = make_float4(acc[i][4] + bias1.x, acc[i][5] + bias1.y,
                                    acc[i][6] + bias1.z, acc[i][7] + bias1.w);
            *(float4*)&out[r * DQK + d0 + tx * 4] = o0;
            *(float4*)&out[r * DQK + d0 + 64 + tx * 4] = o1;
        }
        return;
    }

    // ---------------- MFMA coarse top-8 path ----------------
    // block: 64 rows x (TPS x 128 cands). wave w: rows r0+w*16..+15.
    // C layout: col=lane&15, row=(lane>>4)*4+reg  [m89/m120-verified]
    // Scores carried as packed u32 keys: bits of (sim+16.0) with low 6 bits
    // replaced by local id (tile*8+ch). Bias via MFMA C-init (free);
    // truncation 16*2^-17 ~ 1.2e-4 << bf16-score noise. Branchless top-3
    // insert = 3 umax + 2 umin; merge = pure u32 max-reduce.
    int id = blockIdx.x - QKV_BLOCKS;
    int rb = id % 96, sp = id / 96;
    int r0 = rb * 64;
    int w = t >> 6, lane = t & 63, lq = lane >> 4, lc = lane & 15;

    short* Ah = (short*)smem;            // [64][64] bf16 row-major, 8 KB
    short* Bh = Ah + 64 * EDIM;          // [128][BSTR=72] bf16 padded, 18 KB

    { // stage A from fp32 Qm (once per block): thread covers 16 floats
        int row = t >> 2, seg = t & 3;
        const float4* src = (const float4*)&Qm[(size_t)(r0 + row) * EDIM + seg * 16];
        float4 f0 = src[0], f1 = src[1], f2 = src[2], f3 = src[3];
        int4 p0, p1;
        p0.x = pack2(f0.x, f0.y); p0.y = pack2(f0.z, f0.w);
        p0.z = pack2(f1.x, f1.y); p0.w = pack2(f1.z, f1.w);
        p1.x = pack2(f2.x, f2.y); p1.y = pack2(f2.z, f2.w);
        p1.z = pack2(f3.x, f3.y); p1.w = pack2(f3.z, f3.w);
        *(int4*)&Ah[row * EDIM + seg * 16] = p0;
        *(int4*)&Ah[row * EDIM + seg * 16 + 8] = p1;
    }

    // per-thread B staging coords: v = t + 256*rep; row = v>>3, slot = v&7 (int4 of bf16)
    int4 pr[4];
    { // prefetch tile 0 (already bf16 -> pure copy, no conversion)
        int c0 = (sp * TPS) * 128;
#pragma unroll
        for (int rep = 0; rep < 4; ++rep) {
            int v = t + 256 * rep;
            pr[rep] = *(const int4*)&eg2h[(size_t)(c0 + (v >> 3)) * EDIM + (v & 7) * 8];
        }
    }

    unsigned t3[4][3];
#pragma unroll
    for (int i = 0; i < 4; ++i)
#pragma unroll
        for (int k = 0; k < 3; ++k) t3[i][k] = 0u;

    const unsigned KMASK = 0xFFFFFFC0u;
    bf16x8 af0, af1;
    for (int tile = 0; tile < TPS; ++tile) {
        __syncthreads();    // previous tile's B consumed (tile0: A-store also drains)
#pragma unroll
        for (int rep = 0; rep < 4; ++rep) {
            int v = t + 256 * rep;
            *(int4*)&Bh[(v >> 3) * BSTR + (v & 7) * 8] = pr[rep];
        }
        if (tile + 1 < TPS) { // prefetch next tile; lands during this tile's compute
            int c1 = (sp * TPS + tile + 1) * 128;
#pragma unroll
            for (int rep = 0; rep < 4; ++rep) {
                int v = t + 256 * rep;
                pr[rep] = *(const int4*)&eg2h[(size_t)(c1 + (v >> 3)) * EDIM + (v & 7) * 8];
            }
        }
        __syncthreads();
        if (tile == 0) {
            af0 = *(const bf16x8*)&Ah[(w * 16 + lc) * EDIM + lq * 8];
            af1 = *(const bf16x8*)&Ah[(w * 16 + lc) * EDIM + 32 + lq * 8];
        }

        int tb = tile * 8;
#pragma unroll
        for (int ch = 0; ch < 8; ++ch) {
            bf16x8 b0 = *(const bf16x8*)&Bh[(ch * 16 + lc) * BSTR + lq * 8];
            bf16x8 b1 = *(const bf16x8*)&Bh[(ch * 16 + lc) * BSTR + 32 + lq * 8];
            f32x4 acc = {16.f, 16.f, 16.f, 16.f};   // bias so keys sort as unsigned
            acc = __builtin_amdgcn_mfma_f32_16x16x32_bf16(af0, b0, acc, 0, 0, 0);
            acc = __builtin_amdgcn_mfma_f32_16x16x32_bf16(af1, b1, acc, 0, 0, 0);
            unsigned lid = (unsigned)(tb + ch);
#pragma unroll
            for (int reg = 0; reg < 4; ++reg) {
                unsigned key = (__float_as_uint(acc[reg]) & KMASK) | lid;
                unsigned v0 = t3[reg][0], v1 = t3[reg][1], v2 = t3[reg][2];
                t3[reg][0] = umax(v0, key);
                t3[reg][1] = umax(v1, umin(v0, key));
                t3[reg][2] = umax(v2, umin(v1, key));
            }
        }
    }

    // merge 16 lanes' top-3 -> split top-8: 8 rounds of u32 max-reduce.
    // compare value = (key & ~63) | (lc<<2): unique per lane -> exactly one winner;
    // winner decodes global cand index from its own key (lid = tile*8+ch, own lc).
    int sb128 = sp * (TPS * 128);
    unsigned lc2 = (unsigned)(lc << 2);
#pragma unroll
    for (int i = 0; i < 4; ++i) {
        int row = r0 + w * 16 + lq * 4 + i;
        int base = (row * SPLITS + sp) * CK;
        unsigned a0 = t3[i][0], a1 = t3[i][1], a2 = t3[i][2];
#pragma unroll
        for (int k = 0; k < CK; ++k) {
            unsigned vk = (a0 & KMASK) | lc2;
            unsigned bvv = vk;
#pragma unroll
            for (int off = 1; off < 16; off <<= 1)
                bvv = umax(bvv, (unsigned)__shfl_xor((int)bvv, off, 64));
            if (vk == bvv) {
                unsigned lid = a0 & 63u;
                pidx[base + k] = sb128 + (int)((lid >> 3) << 7) + (int)((lid & 7) << 4) + lc;
                a0 = a1; a1 = a2; a2 = 0u;
            }
        }
    }
}

// ================================================================ exact rescore (coalesced) + top-5 + attention
__global__ __launch_bounds__(TPB) void attn_kernel(
        const float* __restrict__ Qm, const float* __restrict__ ego2,
        const float* __restrict__ Qa, const float* __restrict__ Ka, const float* __restrict__ Va,
        const int* __restrict__ pidx, float* __restrict__ out) {
    __shared__ float sb[4][64];
    int wv = threadIdx.x >> 6, lane = threadIdx.x & 63;
    int r = blockIdx.x * 4 + wv;
    int ci0 = pidx[r * (SPLITS * CK) + lane];     // lane's cand (64 unique: splits partition cands)
    int part = lane & 3;

    const float4* qmp = (const float4*)(Qm + (size_t)r * EDIM + part * 16);
    float4 q0 = qmp[0], q1 = qmp[1], q2 = qmp[2], q3 = qmp[3];

#pragma unroll
    for (int p = 0; p < 4; ++p) {
        int j = p * 16 + (lane >> 2);
        int c = __shfl(ci0, j, 64);
        const float4* ep = (const float4*)(ego2 + (size_t)c * EDIM + part * 16);
        float4 e0 = ep[0], e1 = ep[1], e2 = ep[2], e3 = ep[3];
        float s = 0.f;
        s = fmaf(q0.x, e0.x, s); s = fmaf(q0.y, e0.y, s); s = fmaf(q0.z, e0.z, s); s = fmaf(q0.w, e0.w, s);
        s = fmaf(q1.x, e1.x, s); s = fmaf(q1.y, e1.y, s); s = fmaf(q1.z, e1.z, s); s = fmaf(q1.w, e1.w, s);
        s = fmaf(q2.x, e2.x, s); s = fmaf(q2.y, e2.y, s); s = fmaf(q2.z, e2.z, s); s = fmaf(q2.w, e2.w, s);
        s = fmaf(q3.x, e3.x, s); s = fmaf(q3.y, e3.y, s); s = fmaf(q3.z, e3.z, s); s = fmaf(q3.w, e3.w, s);
        s += __shfl_xor(s, 1, 64);
        s += __shfl_xor(s, 2, 64);
        if (part == 0) sb[wv][j] = s;
    }
    float sv = sb[wv][lane];

    float prevv = INFINITY; int previ = -1;
    int cI[KTOP];
#pragma unroll
    for (int k = 0; k < KTOP; ++k) {
        bool adm = (sv < prevv) || (sv == prevv && ci0 > previ);
        float bv = adm ? sv : -INFINITY;
        int   bi = adm ? ci0 : 0x7fffffff;
#pragma unroll
        for (int off = 1; off < 64; off <<= 1) {
            float ov = __shfl_xor(bv, off, 64);
            int   oi = __shfl_xor(bi, off, 64);
            if (ov > bv || (ov == bv && oi < bi)) { bv = ov; bi = oi; }
        }
        cI[k] = bi; prevv = bv; previ = bi;
    }

    float4 q = *(const float4*)&Qa[r * DQK + lane * 4];
    float sc[KTOP];
#pragma unroll
    for (int k = 0; k < KTOP; ++k) {
        float4 kk = *(const float4*)&Ka[cI[k] * DQK + lane * 4];
        float p = q.x * kk.x + q.y * kk.y + q.z * kk.z + q.w * kk.w;
#pragma unroll
        for (int off = 32; off; off >>= 1) p += __shfl_xor(p, off, 64);
        sc[k] = p * 0.0625f;   // 1/sqrt(256)
    }
    float m = sc[0];
#pragma unroll
    for (int k = 1; k < KTOP; ++k) m = fmaxf(m, sc[k]);
    float wgt[KTOP], ssum = 0.f;
#pragma unroll
    for (int k = 0; k < KTOP; ++k) { wgt[k] = expf(sc[k] - m); ssum += wgt[k]; }
    float inv = 1.f / ssum;
    float4 o = make_float4(0.f, 0.f, 0.f, 0.f);
#pragma unroll
    for (int k = 0; k < KTOP; ++k) {
        float4 vv = *(const float4*)&Va[cI[k] * DQK + lane * 4];
        float a = wgt[k] * inv;
        o.x = fmaf(a, vv.x, o.x); o.y = fmaf(a, vv.y, o.y);
        o.z = fmaf(a, vv.z, o.z); o.w = fmaf(a, vv.w, o.w);
    }
    *(float4*)&out[r * DQK + lane * 4] = o;
}

// ================================================================ launch
extern "C" void kernel_launch(void* const* d_in, const int* in_sizes, int n_in,
                              void* d_out, int out_size, void* d_ws, size_t ws_size,
                              hipStream_t stream) {
    const float* user  = (const float*)d_in[0];
    const float* item  = (const float*)d_in[1];
    const int*   nrows = (const int*)d_in[2];
    const int*   ncols = (const int*)d_in[3];
    const float* nvals = (const float*)d_in[4];
    const int*   arows = (const int*)d_in[5];
    const int*   acols = (const int*)d_in[6];
    const float* Wq = (const float*)d_in[8];  const float* bq = (const float*)d_in[9];
    const float* Wk = (const float*)d_in[10]; const float* bk = (const float*)d_in[11];
    const float* Wv = (const float*)d_in[12]; const float* bv = (const float*)d_in[13];
    float* out = (float*)d_out;
    float* ws  = (float*)d_ws;

    const int NE  = NN * EDIM;             // 393216
    const int NQK = NN * DQK;              // 1572864
    float* ego1 = ws;
    float* ego2 = ws + NE;
    float* Qm   = ws + 2 * NE;
    float* Qa   = ws + 3 * NE;
    float* Ka   = Qa + NQK;
    float* Va   = Ka + NQK;
    int*   pidx = (int*)(Va + NQK);                       // NN*SPLITS*CK ints
    unsigned short* eg2h = (unsigned short*)(pidx + NN * SPLITS * CK);  // NN*EDIM bf16

    // ELL scratch aliased over Qa..Va (dead until qkv_topk)
    int* ell    = (int*)Qa;
    int* cnt_n  = ell;                     // 6144
    int* cnt_a  = ell + 6144;              // 6144
    long long* cv_n = (long long*)(ell + 12288);   // 6144*96 x 8B
    int* cv_a   = (int*)(cv_n + NN * ELLW);        // 6144*96 x 4B

    hipMemsetAsync(cnt_n, 0, 12288 * sizeof(int), stream);
    build_kernel<<<(2 * NNZ + TPB - 1) / TPB, TPB, 0, stream>>>(nrows, ncols, nvals,
                                                                arows, acols,
                                                                cnt_n, cnt_a, cv_n, cv_a);
    spmm_ell_emb_kernel<<<NN / 4, TPB, 0, stream>>>(cnt_n, cv_n, user, item, ego1);
    spmm_ell_kernel<<<NN / 4, TPB, 0, stream>>>(cnt_n, cv_n, ego1, ego2, eg2h);
    qm_mean_kernel<<<NN / 4, TPB, 0, stream>>>(cnt_a, cv_a, ego2, ego1, user, item, Qm, out);
    qkv_topk_kernel<<<QKV_BLOCKS + TOPK_BLOCKS, TPB, 0, stream>>>(
        ego2, eg2h, Wq, bq, Wk, bk, Wv, bv, Qa, Ka, Va, Qm, pidx);
    attn_kernel<<<NN / 4, TPB, 0, stream>>>(Qm, ego2, Qa, Ka, Va, pidx, out + NE);
}